// Round 15
// baseline (257.228 us; speedup 1.0000x reference)
//
#include <hip/hip_runtime.h>
#include <math.h>

#define S_LEN 4096
#define DMODEL 2048
#define NH 16
#define NKVH 4
#define HD 128
#define LDQKV 3072   // NH*HD + 2*NKVH*HD

typedef __attribute__((ext_vector_type(4))) float f32x4;
typedef __attribute__((ext_vector_type(8))) short bf16x8;
typedef __attribute__((ext_vector_type(8))) unsigned short us8;
typedef __attribute__((ext_vector_type(4))) unsigned short us4;

static __device__ __forceinline__ unsigned short f2bf(float f) {
  unsigned int u = __builtin_bit_cast(unsigned int, f);
  u += 0x7fffu + ((u >> 16) & 1u);
  return (unsigned short)(u >> 16);
}
static __device__ __forceinline__ float bf2f(unsigned short h) {
  unsigned int u = ((unsigned int)h) << 16;
  return __builtin_bit_cast(float, u);
}
static __device__ __forceinline__ unsigned int cvt_pk_bf16(float lo, float hi) {
  unsigned int r;
  asm("v_cvt_pk_bf16_f32 %0, %1, %2" : "=v"(r) : "v"(lo), "v"(hi));
  return r;
}

#define GLDS16(g, l) __builtin_amdgcn_global_load_lds( \
    (__attribute__((address_space(1))) void*)(g), \
    (__attribute__((address_space(3))) void*)(l), 16, 0, 0)

// ---------------- prep: cast hidden to bf16 + transpose all weights ----------------

__global__ __launch_bounds__(256) void k_prep(
    const float* __restrict__ hid, unsigned short* __restrict__ Xb,
    const float* __restrict__ Wq, const float* __restrict__ Wk,
    const float* __restrict__ Wv, const float* __restrict__ Wo,
    unsigned short* __restrict__ Wt, unsigned short* __restrict__ Wot) {
  __shared__ float tile[64][65];
  const int b = blockIdx.x, t = threadIdx.x;
  if (b < 8192) {
    int i = b * 256 + t;
    const float4* s = (const float4*)hid;
    float4 v = s[i];
    us4 o = { f2bf(v.x), f2bf(v.y), f2bf(v.z), f2bf(v.w) };
    *(us4*)(Xb + (size_t)i * 4) = o;
    return;
  }
  const int bb = b - 8192;
  const float* src;
  unsigned short* dst;
  int N, c;
  if (bb < 1024)      { src = Wq; dst = Wt;                       N = 2048; c = bb; }
  else if (bb < 1280) { src = Wk; dst = Wt + (size_t)2048 * 2048; N = 512;  c = bb - 1024; }
  else if (bb < 1536) { src = Wv; dst = Wt + (size_t)2560 * 2048; N = 512;  c = bb - 1280; }
  else                { src = Wo; dst = Wot;                      N = 2048; c = bb - 1536; }
  const int k0 = (c & 31) * 64, n0 = (c >> 5) * 64;
#pragma unroll
  for (int i = 0; i < 16; ++i) {
    int idx = t + i * 256;
    int r = idx >> 6, cc = idx & 63;
    tile[r][cc] = src[(size_t)(k0 + r) * N + n0 + cc];
  }
  __syncthreads();
#pragma unroll
  for (int i = 0; i < 16; ++i) {
    int idx = t + i * 256;
    int r = idx >> 6, cc = idx & 63;
    dst[(size_t)(n0 + r) * 2048 + k0 + cc] = f2bf(tile[cc][r]);
  }
}

// ---------------- V-transpose (permuted) ----------------
// Vt[(c0+r)*S + s0+cc] = QKV[s0 + pi(cc)][2560 + c0 + r], pi(cc)=(cc&3)*16+(cc>>2)

__global__ __launch_bounds__(256) void k_vt(
    const unsigned short* __restrict__ QKV, unsigned short* __restrict__ Vt) {
  __shared__ unsigned short tile[64][72];
  const int b = blockIdx.x, t = threadIdx.x;
  const int s0 = (b & 63) * 64, c0 = (b >> 6) * 64;
#pragma unroll
  for (int i = 0; i < 16; ++i) {
    int idx = t + i * 256;
    int r = idx >> 6, cc = idx & 63;
    tile[r][cc] = QKV[(size_t)(s0 + r) * LDQKV + DMODEL + NKVH * HD + c0 + cc];
  }
  __syncthreads();
#pragma unroll
  for (int i = 0; i < 16; ++i) {
    int idx = t + i * 256;
    int r = idx >> 6, cc = idx & 63;
    int pc = (cc & 3) * 16 + (cc >> 2);
    Vt[(size_t)(c0 + r) * S_LEN + s0 + cc] = tile[pc][r];
  }
}

// ---------------- 2-phase/K-tile GEMM: C[M][N] = A[M][K] * Bt[N][K]^T ----------------
// BM=256, BN=128, BK=64, 512 threads / 8 waves, each wave owns 32 rows x 128 cols.
// Triple-buffered LDS (144 KB), 16 MFMA per barrier-pair, counted vmcnt(6)
// (6 loads/tile/wave: allow ONLY the next tile's 6 in flight -> current tile
// drained; r13's vmcnt(12) was a no-op wait = race, absmax 0.13).
// MODE 1: QKV epilogue (RoPE on Q/K in f32, bf16 out); MODE 2: f32 out.

#define STG_A(kt_, buf_, j_) do { \
  const int row_ = (j_) * 64 + srow; \
  GLDS16(A + (size_t)(bm + row_) * K + (kt_) * 64 + ((gsel ^ (srow & 7)) * 8), \
         (char*)Ab[buf_] + (j_) * 8192 + wave * 1024); \
} while (0)
#define STG_B(kt_, buf_, j_) do { \
  const int row_ = (j_) * 64 + srow; \
  GLDS16(Bt + (size_t)(bn + row_) * K + (kt_) * 64 + ((gsel ^ (srow & 7)) * 8), \
         (char*)Bb[buf_] + (j_) * 8192 + wave * 1024); \
} while (0)

template<int MODE>
__global__ __launch_bounds__(512, 1) void k_gemm8(
    const unsigned short* __restrict__ A, const unsigned short* __restrict__ Bt,
    void* __restrict__ Cp, int M, int N, int K, int nbm, int nbn,
    const float* __restrict__ cp, const float* __restrict__ sp) {
  __shared__ __attribute__((aligned(16))) unsigned short Ab[3][256 * 64];
  __shared__ __attribute__((aligned(16))) unsigned short Bb[3][128 * 64];
  const int t = threadIdx.x, wave = t >> 6, lane = t & 63;
  const int lr = lane & 15, lg = lane >> 4;
  const int srow = wave * 8 + (lane >> 3);
  const int gsel = lane & 7;
  // bijective XCD swizzle (grid %8==0 for both calls), m-major chunks
  const int nwg = nbm * nbn;
  const int q8 = nwg >> 3;
  const int wg = (blockIdx.x & 7) * q8 + (blockIdx.x >> 3);
  const int bm = (wg % nbm) * 256, bn = (wg / nbm) * 128;
  const int wr = wave * 32;

  f32x4 acc[2][8];
#pragma unroll
  for (int i = 0; i < 2; ++i)
#pragma unroll
    for (int j = 0; j < 8; ++j) acc[i][j] = (f32x4){0.f, 0.f, 0.f, 0.f};

  // prologue: stage K-tiles 0 and 1 (6 units each); tile 0 must land -> vmcnt(6)
#pragma unroll
  for (int tt = 0; tt < 2; ++tt) {
    STG_A(tt, tt, 0); STG_A(tt, tt, 1); STG_A(tt, tt, 2); STG_A(tt, tt, 3);
    STG_B(tt, tt, 0); STG_B(tt, tt, 1);
  }
  asm volatile("s_waitcnt vmcnt(6)" ::: "memory");   // tile 0 landed (tile 1 in flight)
  __builtin_amdgcn_s_barrier();

  const int nkt = K >> 6;
  for (int kt = 0; kt < nkt; ++kt) {
    const int cur = kt % 3;
    const int nx = (kt + 2) % 3;
    const unsigned short* Ac = Ab[cur];
    const unsigned short* Bc = Bb[cur];
    const bool stg = kt < nkt - 2;

    // ---- P1: read A(mi=0) + all B; stage 3 units; 16 MFMA ----
    bf16x8 aq[2], bq[8][2];
#pragma unroll
    for (int ks = 0; ks < 2; ++ks)
      aq[ks] = *(const bf16x8*)(Ac + (wr + lr) * 64 + (((ks * 4 + lg) ^ (lr & 7)) * 8));
#pragma unroll
    for (int nf = 0; nf < 8; ++nf)
#pragma unroll
      for (int ks = 0; ks < 2; ++ks)
        bq[nf][ks] = *(const bf16x8*)(Bc + (nf * 16 + lr) * 64 + (((ks * 4 + lg) ^ (lr & 7)) * 8));
    if (stg) { STG_A(kt + 2, nx, 0); STG_A(kt + 2, nx, 1); STG_B(kt + 2, nx, 0); }
    __builtin_amdgcn_s_barrier();
    __builtin_amdgcn_s_setprio(1);
#pragma unroll
    for (int nf = 0; nf < 8; ++nf)
#pragma unroll
      for (int ks = 0; ks < 2; ++ks)
        acc[0][nf] = __builtin_amdgcn_mfma_f32_16x16x32_bf16(aq[ks], bq[nf][ks], acc[0][nf], 0, 0, 0);
    __builtin_amdgcn_s_setprio(0);
    __builtin_amdgcn_s_barrier();

    // ---- P2: read A(mi=1) (B reused from regs); stage 3 units; 16 MFMA ----
#pragma unroll
    for (int ks = 0; ks < 2; ++ks)
      aq[ks] = *(const bf16x8*)(Ac + (wr + 16 + lr) * 64 + (((ks * 4 + lg) ^ (lr & 7)) * 8));
    if (stg) { STG_A(kt + 2, nx, 2); STG_A(kt + 2, nx, 3); STG_B(kt + 2, nx, 1); }
    __builtin_amdgcn_s_barrier();
    __builtin_amdgcn_s_setprio(1);
#pragma unroll
    for (int nf = 0; nf < 8; ++nf)
#pragma unroll
      for (int ks = 0; ks < 2; ++ks)
        acc[1][nf] = __builtin_amdgcn_mfma_f32_16x16x32_bf16(aq[ks], bq[nf][ks], acc[1][nf], 0, 0, 0);
    __builtin_amdgcn_s_setprio(0);
    if (stg)                  asm volatile("s_waitcnt vmcnt(6)" ::: "memory");  // tile kt+1 landed
    else if (kt == nkt - 2)   asm volatile("s_waitcnt vmcnt(0)" ::: "memory");
    __builtin_amdgcn_s_barrier();
  }

  // ---- epilogue (identical layout to the proven k_gemm_bt) ----
  if (MODE == 1 && bn < NKVH * HD + DMODEL) {
    const float qs = bn < DMODEL ? 0.12751589341664477f : 1.0f;  // log2e/sqrt(128) on Q
    unsigned short* o = (unsigned short*)Cp;
#pragma unroll
    for (int mi = 0; mi < 2; ++mi)
#pragma unroll
      for (int r = 0; r < 4; ++r) {
        const int m = bm + wr + mi * 16 + lg * 4 + r;
#pragma unroll
        for (int ni = 0; ni < 4; ++ni) {
          const int d = ni * 16 + lr;
          const float c = cp[m * HD + d], s = sp[m * HD + d];
          const float x1 = acc[mi][ni][r], x2 = acc[mi][ni + 4][r];
          o[(size_t)m * N + bn + d]      = f2bf((x1 * c - x2 * s) * qs);
          o[(size_t)m * N + bn + d + 64] = f2bf((x2 * c + x1 * s) * qs);
        }
      }
    return;
  }
#pragma unroll
  for (int mi = 0; mi < 2; ++mi)
#pragma unroll
    for (int ni = 0; ni < 8; ++ni)
#pragma unroll
      for (int r = 0; r < 4; ++r) {
        const int m = bm + wr + mi * 16 + lg * 4 + r;
        const int n = bn + ni * 16 + lr;
        if (MODE == 2) ((float*)Cp)[(size_t)m * N + n] = acc[mi][ni][r];
        else ((unsigned short*)Cp)[(size_t)m * N + n] = f2bf(acc[mi][ni][r]);
      }
}

// ---------------- fused causal gated attention (v12: kv-split, unchanged) ----------------

#define STAGE_KV(kt_, buf_) do { \
  const int kv0_ = (kt_) * 64; \
  _Pragma("unroll") \
  for (int i_ = 0; i_ < 2; ++i_) { \
    const int cb_ = (wave * 2 + i_) * 64; \
    const int c_ = cb_ + lane; \
    { const int row_ = c_ >> 4, kc_ = c_ & 15; \
      GLDS16(Kp + (size_t)(kv0_ + row_) * LDQKV + ((kc_ ^ (row_ & 7)) * 8), \
             (char*)Ks[buf_] + cb_ * 16); } \
    { const int d_ = c_ >> 3, kc_ = c_ & 7; \
      GLDS16(Vp + (size_t)d_ * S_LEN + kv0_ + ((kc_ ^ (d_ & 7)) * 8), \
             (char*)Vs[buf_] + cb_ * 16); } \
  } \
} while (0)

__global__ __launch_bounds__(512) void k_attn(
    const unsigned short* __restrict__ QKV, const unsigned short* __restrict__ Vt,
    const float* __restrict__ gate, unsigned short* __restrict__ N1,
    unsigned short* __restrict__ N2, float2* __restrict__ Ms) {
  __shared__ __attribute__((aligned(16))) unsigned short Ks[2][64 * 128];
  __shared__ __attribute__((aligned(16))) unsigned short Vs[2][128 * 64];
  __shared__ __attribute__((aligned(16))) unsigned short Ps[8][2][16][72];
  const int bx = blockIdx.x;
  const int st = 15 - (bx >> 5);
  const int rem = bx & 31;
  const int h = rem >> 1, chunk = rem & 1;
  const int kvh = h >> 2;
  const int t = threadIdx.x, wave = t >> 6, lane = t & 63;
  const int lr = lane & 15, lg = lane >> 4;
  const unsigned short* Qp = QKV + h * HD;
  const unsigned short* Kp = QKV + DMODEL + kvh * HD;
  const unsigned short* Vp = Vt + (size_t)kvh * HD * S_LEN;
  bf16x8 vb_ones;
  {
    const short one = (short)0x3F80, z = 0;
    const short e = (lr == 0) ? one : z;
    vb_ones = (bf16x8){e, e, e, e, e, e, e, e};
  }

  const int q0 = st * 256;
  const int half_nt = 2 * st + 2;
  const int kt_lo = chunk * half_nt, kt_hi = kt_lo + half_nt;
  const int qb[2] = { q0 + wave * 32 + lg * 4, q0 + wave * 32 + 16 + lg * 4 };

  bf16x8 qf[2][4];
#pragma unroll
  for (int g = 0; g < 2; ++g) {
    const size_t qoff = (size_t)(q0 + wave * 32 + g * 16 + lr) * LDQKV;
#pragma unroll
    for (int ks = 0; ks < 4; ++ks)
      qf[g][ks] = *(const bf16x8*)(Qp + qoff + ks * 32 + lg * 8);
  }
  f32x4 acc[2][8];
#pragma unroll
  for (int g = 0; g < 2; ++g)
#pragma unroll
    for (int j = 0; j < 8; ++j) acc[g][j] = (f32x4){0.f, 0.f, 0.f, 0.f};
  f32x4 acc_s[2] = { (f32x4){0.f, 0.f, 0.f, 0.f}, (f32x4){0.f, 0.f, 0.f, 0.f} };
  float mrow[2][4] = { {-3e38f, -3e38f, -3e38f, -3e38f}, {-3e38f, -3e38f, -3e38f, -3e38f} };
  f32x4 sc[2][4];
  float g4[4];

  STAGE_KV(kt_lo, kt_lo & 1);

  for (int kt = kt_lo; kt < kt_hi; ++kt) {
    const int kv0 = kt * 64;
    if (kt + 1 < kt_hi) {
      STAGE_KV(kt + 1, (kt + 1) & 1);
      asm volatile("s_waitcnt vmcnt(4)" ::: "memory");
    } else {
      asm volatile("s_waitcnt vmcnt(0)" ::: "memory");
    }
    __builtin_amdgcn_s_barrier();
    const unsigned short* Kb = Ks[kt & 1];
    const unsigned short* Vb = Vs[kt & 1];
#pragma unroll
    for (int cf = 0; cf < 4; ++cf) g4[cf] = gate[kv0 + cf * 16 + lr];

    // dual QK^T: each kb read feeds both row-groups
    __builtin_amdgcn_s_setprio(1);
#pragma unroll
    for (int cf = 0; cf < 4; ++cf) {
      sc[0][cf] = (f32x4){0.f, 0.f, 0.f, 0.f};
      sc[1][cf] = (f32x4){0.f, 0.f, 0.f, 0.f};
      const int row = cf * 16 + lr;
#pragma unroll
      for (int ks = 0; ks < 4; ++ks) {
        bf16x8 kb = *(const bf16x8*)(Kb + row * 128 + (((ks * 4 + lg) ^ (lr & 7)) * 8));
        sc[0][cf] = __builtin_amdgcn_mfma_f32_16x16x32_bf16(qf[0][ks], kb, sc[0][cf], 0, 0, 0);
        sc[1][cf] = __builtin_amdgcn_mfma_f32_16x16x32_bf16(qf[1][ks], kb, sc[1][cf], 0, 0, 0);
      }
    }
    __builtin_amdgcn_s_setprio(0);

    const bool tail = kv0 >= q0;
    // per-group softmax + P write
#pragma unroll
    for (int g = 0; g < 2; ++g) {
      if (tail) {
#pragma unroll
        for (int cf = 0; cf < 4; ++cf) {
          const int kpos = kv0 + cf * 16 + lr;
#pragma unroll
          for (int r = 0; r < 4; ++r)
            sc[g][cf][r] = (kpos <= qb[g] + r) ? sc[g][cf][r] : -3e38f;
        }
      }
      float lmax[4];
#pragma unroll
      for (int r = 0; r < 4; ++r)
        lmax[r] = fmaxf(fmaxf(sc[g][0][r], sc[g][1][r]), fmaxf(sc[g][2][r], sc[g][3][r]));
      bool need = (lmax[0] > mrow[g][0] + 11.5416f) | (lmax[1] > mrow[g][1] + 11.5416f) |
                  (lmax[2] > mrow[g][2] + 11.5416f) | (lmax[3] > mrow[g][3] + 11.5416f);
      if (__any(need)) {
        float tm[4] = {lmax[0], lmax[1], lmax[2], lmax[3]};
#pragma unroll
        for (int off = 8; off; off >>= 1)
#pragma unroll
          for (int r = 0; r < 4; ++r) tm[r] = fmaxf(tm[r], __shfl_xor(tm[r], off));
#pragma unroll
        for (int r = 0; r < 4; ++r) {
          const float mn = fmaxf(mrow[g][r], tm[r]);
          const float alpha = __builtin_amdgcn_exp2f(mrow[g][r] - mn);
          mrow[g][r] = mn;
#pragma unroll
          for (int j = 0; j < 8; ++j) acc[g][j][r] *= alpha;
          acc_s[g][r] *= alpha;
        }
      }
#pragma unroll
      for (int r = 0; r < 4; ++r) {
        float p0 = __builtin_amdgcn_exp2f(sc[g][0][r] - mrow[g][r]) * g4[0];
        float p1 = __builtin_amdgcn_exp2f(sc[g][1][r] - mrow[g][r]) * g4[1];
        float p2 = __builtin_amdgcn_exp2f(sc[g][2][r] - mrow[g][r]) * g4[2];
        float p3 = __builtin_amdgcn_exp2f(sc[g][3][r] - mrow[g][r]) * g4[3];
        uint2 pk = { cvt_pk_bf16(p0, p1), cvt_pk_bf16(p2, p3) };
        *(uint2*)(&Ps[wave][g][lg * 4 + r][lr * 4]) = pk;
      }
    }
    // shared PV: each vb read feeds both row-groups
    __builtin_amdgcn_s_setprio(1);
#pragma unroll
    for (int ks = 0; ks < 2; ++ks) {
      bf16x8 pa0 = *(const bf16x8*)(&Ps[wave][0][lr][ks * 32 + lg * 8]);
      bf16x8 pa1 = *(const bf16x8*)(&Ps[wave][1][lr][ks * 32 + lg * 8]);
#pragma unroll
      for (int j = 0; j < 8; ++j) {
        const int d = j * 16 + lr;
        bf16x8 vb = *(const bf16x8*)(Vb + d * 64 + (((ks * 4 + lg) ^ (lr & 7)) * 8));
        acc[0][j] = __builtin_amdgcn_mfma_f32_16x16x32_bf16(pa0, vb, acc[0][j], 0, 0, 0);
        acc[1][j] = __builtin_amdgcn_mfma_f32_16x16x32_bf16(pa1, vb, acc[1][j], 0, 0, 0);
      }
      acc_s[0] = __builtin_amdgcn_mfma_f32_16x16x32_bf16(pa0, vb_ones, acc_s[0], 0, 0, 0);
      acc_s[1] = __builtin_amdgcn_mfma_f32_16x16x32_bf16(pa1, vb_ones, acc_s[1], 0, 0, 0);
    }
    __builtin_amdgcn_s_setprio(0);
    __builtin_amdgcn_s_barrier();
  }

  // partial epilogue: unnormalized numerator + (m, s) per row
  unsigned short* Nd = chunk ? N2 : N1;
#pragma unroll
  for (int g = 0; g < 2; ++g) {
#pragma unroll
    for (int j = 0; j < 8; ++j)
#pragma unroll
      for (int r = 0; r < 4; ++r)
        Nd[(size_t)(qb[g] + r) * DMODEL + h * HD + j * 16 + lr] = f2bf(acc[g][j][r]);
  }
  if (lr == 0) {
#pragma unroll
    for (int g = 0; g < 2; ++g)
#pragma unroll
      for (int r = 0; r < 4; ++r)
        Ms[(size_t)(chunk * 16 + h) * S_LEN + qb[g] + r] =
            make_float2(mrow[g][r], acc_s[g][r]);
  }
}

// ---------------- combine: O = (w1 N1 + w2 N2) / (w1 s1 + w2 s2) ----------------

__global__ __launch_bounds__(256) void k_comb(
    unsigned short* __restrict__ N1, const unsigned short* __restrict__ N2,
    const float2* __restrict__ Ms) {
  const int gid = blockIdx.x * 256 + threadIdx.x;
  const size_t e = (size_t)gid * 8;
  const int row = (int)(e >> 11);
  const int col = (int)(e & 2047);
  const int h = col >> 7;
  const float2 a = Ms[(size_t)h * S_LEN + row];
  const float2 b = Ms[(size_t)(16 + h) * S_LEN + row];
  const float m = fmaxf(a.x, b.x);
  const float w1 = __builtin_amdgcn_exp2f(a.x - m);
  const float w2 = __builtin_amdgcn_exp2f(b.x - m);
  const float inv = 1.0f / (w1 * a.y + w2 * b.y);
  us8 n1 = *(const us8*)(N1 + e);
  us8 n2 = *(const us8*)(N2 + e);
  us8 o;
#pragma unroll
  for (int k = 0; k < 8; ++k)
    o[k] = f2bf((w1 * bf2f(n1[k]) + w2 * bf2f(n2[k])) * inv);
  *(us8*)(N1 + e) = o;
}

// ---------------- launch ----------------

extern "C" void kernel_launch(void* const* d_in, const int* in_sizes, int n_in,
                              void* d_out, int out_size, void* d_ws, size_t ws_size,
                              hipStream_t stream) {
  (void)in_sizes; (void)n_in; (void)out_size; (void)ws_size;
  const float* hid  = (const float*)d_in[0];
  // d_in[1] = attention_mask (pure causal; recomputed inline, never read)
  const float* cosp = (const float*)d_in[2];
  const float* sinp = (const float*)d_in[3];
  const float* gate = (const float*)d_in[4];
  const float* Wq   = (const float*)d_in[5];
  const float* Wk   = (const float*)d_in[6];
  const float* Wv   = (const float*)d_in[7];
  const float* Wo   = (const float*)d_in[8];
  float* out = (float*)d_out;
  char* ws = (char*)d_ws;
  unsigned short* Xb   = (unsigned short*)(ws);                       // 16 MB  (dead after GEMM1)
  unsigned short* Wt   = (unsigned short*)(ws + (size_t)16777216);    // 12 MB  (dead after GEMM1)
  unsigned short* Wot  = (unsigned short*)(ws + (size_t)29360128);    //  8 MB  Wo^T
  unsigned short* QKV  = (unsigned short*)(ws + (size_t)37748736);    // 24 MB  [4096][3072] bf16 (roped)
  unsigned short* Oatt = (unsigned short*)(ws + (size_t)62914560);    // 16 MB  (N1 -> O in-place)
  unsigned short* Vt   = (unsigned short*)(ws + (size_t)79691776);    //  4 MB  [4][128][4096] bf16
  unsigned short* Np   = Xb;                                          // 16 MB  chunk-1 numerator
  float2* Ms           = (float2*)Wt;                                 //  1 MB  [2][16][4096] (m,s)

  k_prep<<<10752, 256, 0, stream>>>(hid, Xb, Wq, Wk, Wv, Wo, Wt, Wot);
  k_gemm8<1><<<384, 512, 0, stream>>>(Xb, Wt, QKV, 4096, 3072, 2048, 16, 24, cosp, sinp);
  k_vt<<<512, 256, 0, stream>>>(QKV, Vt);
  k_attn<<<512, 512, 0, stream>>>(QKV, Vt, gate, Oatt, Np, Ms);
  k_comb<<<4096, 256, 0, stream>>>(Oatt, Np, Ms);
  k_gemm8<2><<<256, 512, 0, stream>>>(Oatt, Wot, out, 4096, 2048, 2048, 16, 16, nullptr, nullptr);
}

// Round 16
// 247.060 us; speedup vs baseline: 1.0412x; 1.0412x over previous
//
#include <hip/hip_runtime.h>
#include <math.h>

#define S_LEN 4096
#define DMODEL 2048
#define NH 16
#define NKVH 4
#define HD 128
#define LDQKV 3072   // NH*HD + 2*NKVH*HD

typedef __attribute__((ext_vector_type(4))) float f32x4;
typedef __attribute__((ext_vector_type(8))) short bf16x8;
typedef __attribute__((ext_vector_type(8))) unsigned short us8;
typedef __attribute__((ext_vector_type(4))) unsigned short us4;

static __device__ __forceinline__ unsigned short f2bf(float f) {
  unsigned int u = __builtin_bit_cast(unsigned int, f);
  u += 0x7fffu + ((u >> 16) & 1u);
  return (unsigned short)(u >> 16);
}
static __device__ __forceinline__ float bf2f(unsigned short h) {
  unsigned int u = ((unsigned int)h) << 16;
  return __builtin_bit_cast(float, u);
}
static __device__ __forceinline__ unsigned int cvt_pk_bf16(float lo, float hi) {
  unsigned int r;
  asm("v_cvt_pk_bf16_f32 %0, %1, %2" : "=v"(r) : "v"(lo), "v"(hi));
  return r;
}

#define GLDS16(g, l) __builtin_amdgcn_global_load_lds( \
    (__attribute__((address_space(1))) void*)(g), \
    (__attribute__((address_space(3))) void*)(l), 16, 0, 0)

// ---------------- prep: cast hidden to bf16 + transpose all weights ----------------

__global__ __launch_bounds__(256) void k_prep(
    const float* __restrict__ hid, unsigned short* __restrict__ Xb,
    const float* __restrict__ Wq, const float* __restrict__ Wk,
    const float* __restrict__ Wv, const float* __restrict__ Wo,
    unsigned short* __restrict__ Wt, unsigned short* __restrict__ Wot) {
  __shared__ float tile[64][65];
  const int b = blockIdx.x, t = threadIdx.x;
  if (b < 8192) {
    int i = b * 256 + t;
    const float4* s = (const float4*)hid;
    float4 v = s[i];
    us4 o = { f2bf(v.x), f2bf(v.y), f2bf(v.z), f2bf(v.w) };
    *(us4*)(Xb + (size_t)i * 4) = o;
    return;
  }
  const int bb = b - 8192;
  const float* src;
  unsigned short* dst;
  int N, c;
  if (bb < 1024)      { src = Wq; dst = Wt;                       N = 2048; c = bb; }
  else if (bb < 1280) { src = Wk; dst = Wt + (size_t)2048 * 2048; N = 512;  c = bb - 1024; }
  else if (bb < 1536) { src = Wv; dst = Wt + (size_t)2560 * 2048; N = 512;  c = bb - 1280; }
  else                { src = Wo; dst = Wot;                      N = 2048; c = bb - 1536; }
  const int k0 = (c & 31) * 64, n0 = (c >> 5) * 64;
#pragma unroll
  for (int i = 0; i < 16; ++i) {
    int idx = t + i * 256;
    int r = idx >> 6, cc = idx & 63;
    tile[r][cc] = src[(size_t)(k0 + r) * N + n0 + cc];
  }
  __syncthreads();
#pragma unroll
  for (int i = 0; i < 16; ++i) {
    int idx = t + i * 256;
    int r = idx >> 6, cc = idx & 63;
    dst[(size_t)(n0 + r) * 2048 + k0 + cc] = f2bf(tile[cc][r]);
  }
}

// ---------------- V-transpose (permuted) ----------------
// Vt[(c0+r)*S + s0+cc] = QKV[s0 + pi(cc)][2560 + c0 + r], pi(cc)=(cc&3)*16+(cc>>2)

__global__ __launch_bounds__(256) void k_vt(
    const unsigned short* __restrict__ QKV, unsigned short* __restrict__ Vt) {
  __shared__ unsigned short tile[64][72];
  const int b = blockIdx.x, t = threadIdx.x;
  const int s0 = (b & 63) * 64, c0 = (b >> 6) * 64;
#pragma unroll
  for (int i = 0; i < 16; ++i) {
    int idx = t + i * 256;
    int r = idx >> 6, cc = idx & 63;
    tile[r][cc] = QKV[(size_t)(s0 + r) * LDQKV + DMODEL + NKVH * HD + c0 + cc];
  }
  __syncthreads();
#pragma unroll
  for (int i = 0; i < 16; ++i) {
    int idx = t + i * 256;
    int r = idx >> 6, cc = idx & 63;
    int pc = (cc & 3) * 16 + (cc >> 2);
    Vt[(size_t)(c0 + r) * S_LEN + s0 + cc] = tile[pc][r];
  }
}

// ---------------- GEMM: C[M][N] = A[M][K] * Bt[N][K]^T ----------------
// 128x128 tile, BK=32, 4 waves M-split (32 rows x 128 cols each), 3 blocks/CU.
// Proven m97-class structure (~900 TF) — confirmed twice as the practical
// ceiling for these shapes (r7 and r14/15 restructures both slower).
// MODE 1: QKV epilogue (RoPE on Q/K in f32, bf16 out); MODE 2: f32 out.

template<int MODE>
__global__ __launch_bounds__(256) void k_gemm_bt(
    const unsigned short* __restrict__ A, const unsigned short* __restrict__ Bt,
    void* __restrict__ Cp, int M, int N, int K,
    const float* __restrict__ cp, const float* __restrict__ sp) {
  __shared__ __attribute__((aligned(16))) unsigned short As[128 * 32];
  __shared__ __attribute__((aligned(16))) unsigned short Bs[128 * 32];
  const int t = threadIdx.x;
  const int wave = t >> 6, lane = t & 63;
  const int lr = lane & 15, lg = lane >> 4;
  const int bm = blockIdx.x * 128, bn = blockIdx.y * 128;
  const int wr = wave * 32;
  f32x4 acc[2][8];
#pragma unroll
  for (int i = 0; i < 2; ++i)
#pragma unroll
    for (int j = 0; j < 8; ++j) acc[i][j] = (f32x4){0.f, 0.f, 0.f, 0.f};

  for (int k0 = 0; k0 < K; k0 += 32) {
    __syncthreads();
#pragma unroll
    for (int i = 0; i < 2; ++i) {
      const int cb = (wave * 2 + i) * 64;
      const int c = cb + lane;
      const int row = c >> 2, kc = c & 3;
      const int ksw = (kc ^ (row & 3)) * 8;
      GLDS16(A + (size_t)(bm + row) * K + k0 + ksw, (char*)As + cb * 16);
      GLDS16(Bt + (size_t)(bn + row) * K + k0 + ksw, (char*)Bs + cb * 16);
    }
    asm volatile("s_waitcnt vmcnt(0)" ::: "memory");
    __syncthreads();
    bf16x8 af[2], bfr[8];
#pragma unroll
    for (int mi = 0; mi < 2; ++mi) {
      const int row = wr + mi * 16 + lr;
      af[mi] = *(const bf16x8*)(As + row * 32 + ((lg ^ (lr & 3)) * 8));
    }
#pragma unroll
    for (int ni = 0; ni < 8; ++ni) {
      const int row = ni * 16 + lr;
      bfr[ni] = *(const bf16x8*)(Bs + row * 32 + ((lg ^ (lr & 3)) * 8));
    }
#pragma unroll
    for (int mi = 0; mi < 2; ++mi)
#pragma unroll
      for (int ni = 0; ni < 8; ++ni)
        acc[mi][ni] = __builtin_amdgcn_mfma_f32_16x16x32_bf16(af[mi], bfr[ni], acc[mi][ni], 0, 0, 0);
  }

  if (MODE == 1 && bn < NKVH * HD + DMODEL) {
    const float qs = bn < DMODEL ? 0.12751589341664477f : 1.0f;  // log2e/sqrt(128) on Q
    unsigned short* o = (unsigned short*)Cp;
#pragma unroll
    for (int mi = 0; mi < 2; ++mi)
#pragma unroll
      for (int r = 0; r < 4; ++r) {
        const int m = bm + wr + mi * 16 + lg * 4 + r;
#pragma unroll
        for (int ni = 0; ni < 4; ++ni) {
          const int d = ni * 16 + lr;
          const float c = cp[m * HD + d], s = sp[m * HD + d];
          const float x1 = acc[mi][ni][r], x2 = acc[mi][ni + 4][r];
          o[(size_t)m * N + bn + d]      = f2bf((x1 * c - x2 * s) * qs);
          o[(size_t)m * N + bn + d + 64] = f2bf((x2 * c + x1 * s) * qs);
        }
      }
    return;
  }
#pragma unroll
  for (int mi = 0; mi < 2; ++mi)
#pragma unroll
    for (int ni = 0; ni < 8; ++ni)
#pragma unroll
      for (int r = 0; r < 4; ++r) {
        const int m = bm + wr + mi * 16 + lg * 4 + r;
        const int n = bn + ni * 16 + lr;
        if (MODE == 2) ((float*)Cp)[(size_t)m * N + n] = acc[mi][ni][r];
        else ((unsigned short*)Cp)[(size_t)m * N + n] = f2bf(acc[mi][ni][r]);
      }
}

// ---------------- fused causal gated attention (v12: kv-split) ----------------
// 512 blocks, heavy-first: bx -> st = 15-(bx>>5), h = (bx&31)>>1, chunk = bx&1.
// Block st owns q-rows [st*256, +256) (8 waves x 32 rows, shared kb/vb reads),
// kv tiles [chunk*(2st+2), (chunk+1)*(2st+2)). Writes UNNORMALIZED partial
// numerator (bf16) + per-row (m, s) f32; k_comb merges the two chunks.

#define STAGE_KV(kt_, buf_) do { \
  const int kv0_ = (kt_) * 64; \
  _Pragma("unroll") \
  for (int i_ = 0; i_ < 2; ++i_) { \
    const int cb_ = (wave * 2 + i_) * 64; \
    const int c_ = cb_ + lane; \
    { const int row_ = c_ >> 4, kc_ = c_ & 15; \
      GLDS16(Kp + (size_t)(kv0_ + row_) * LDQKV + ((kc_ ^ (row_ & 7)) * 8), \
             (char*)Ks[buf_] + cb_ * 16); } \
    { const int d_ = c_ >> 3, kc_ = c_ & 7; \
      GLDS16(Vp + (size_t)d_ * S_LEN + kv0_ + ((kc_ ^ (d_ & 7)) * 8), \
             (char*)Vs[buf_] + cb_ * 16); } \
  } \
} while (0)

__global__ __launch_bounds__(512) void k_attn(
    const unsigned short* __restrict__ QKV, const unsigned short* __restrict__ Vt,
    const float* __restrict__ gate, unsigned short* __restrict__ N1,
    unsigned short* __restrict__ N2, float2* __restrict__ Ms) {
  __shared__ __attribute__((aligned(16))) unsigned short Ks[2][64 * 128];
  __shared__ __attribute__((aligned(16))) unsigned short Vs[2][128 * 64];
  __shared__ __attribute__((aligned(16))) unsigned short Ps[8][2][16][72];
  const int bx = blockIdx.x;
  const int st = 15 - (bx >> 5);
  const int rem = bx & 31;
  const int h = rem >> 1, chunk = rem & 1;
  const int kvh = h >> 2;
  const int t = threadIdx.x, wave = t >> 6, lane = t & 63;
  const int lr = lane & 15, lg = lane >> 4;
  const unsigned short* Qp = QKV + h * HD;
  const unsigned short* Kp = QKV + DMODEL + kvh * HD;
  const unsigned short* Vp = Vt + (size_t)kvh * HD * S_LEN;
  bf16x8 vb_ones;
  {
    const short one = (short)0x3F80, z = 0;
    const short e = (lr == 0) ? one : z;
    vb_ones = (bf16x8){e, e, e, e, e, e, e, e};
  }

  const int q0 = st * 256;
  const int half_nt = 2 * st + 2;
  const int kt_lo = chunk * half_nt, kt_hi = kt_lo + half_nt;
  const int qb[2] = { q0 + wave * 32 + lg * 4, q0 + wave * 32 + 16 + lg * 4 };

  bf16x8 qf[2][4];
#pragma unroll
  for (int g = 0; g < 2; ++g) {
    const size_t qoff = (size_t)(q0 + wave * 32 + g * 16 + lr) * LDQKV;
#pragma unroll
    for (int ks = 0; ks < 4; ++ks)
      qf[g][ks] = *(const bf16x8*)(Qp + qoff + ks * 32 + lg * 8);
  }
  f32x4 acc[2][8];
#pragma unroll
  for (int g = 0; g < 2; ++g)
#pragma unroll
    for (int j = 0; j < 8; ++j) acc[g][j] = (f32x4){0.f, 0.f, 0.f, 0.f};
  f32x4 acc_s[2] = { (f32x4){0.f, 0.f, 0.f, 0.f}, (f32x4){0.f, 0.f, 0.f, 0.f} };
  float mrow[2][4] = { {-3e38f, -3e38f, -3e38f, -3e38f}, {-3e38f, -3e38f, -3e38f, -3e38f} };
  f32x4 sc[2][4];
  float g4[4];

  STAGE_KV(kt_lo, kt_lo & 1);

  for (int kt = kt_lo; kt < kt_hi; ++kt) {
    const int kv0 = kt * 64;
    if (kt + 1 < kt_hi) {
      STAGE_KV(kt + 1, (kt + 1) & 1);
      asm volatile("s_waitcnt vmcnt(4)" ::: "memory");
    } else {
      asm volatile("s_waitcnt vmcnt(0)" ::: "memory");
    }
    __builtin_amdgcn_s_barrier();
    const unsigned short* Kb = Ks[kt & 1];
    const unsigned short* Vb = Vs[kt & 1];
#pragma unroll
    for (int cf = 0; cf < 4; ++cf) g4[cf] = gate[kv0 + cf * 16 + lr];

    // dual QK^T: each kb read feeds both row-groups
    __builtin_amdgcn_s_setprio(1);
#pragma unroll
    for (int cf = 0; cf < 4; ++cf) {
      sc[0][cf] = (f32x4){0.f, 0.f, 0.f, 0.f};
      sc[1][cf] = (f32x4){0.f, 0.f, 0.f, 0.f};
      const int row = cf * 16 + lr;
#pragma unroll
      for (int ks = 0; ks < 4; ++ks) {
        bf16x8 kb = *(const bf16x8*)(Kb + row * 128 + (((ks * 4 + lg) ^ (lr & 7)) * 8));
        sc[0][cf] = __builtin_amdgcn_mfma_f32_16x16x32_bf16(qf[0][ks], kb, sc[0][cf], 0, 0, 0);
        sc[1][cf] = __builtin_amdgcn_mfma_f32_16x16x32_bf16(qf[1][ks], kb, sc[1][cf], 0, 0, 0);
      }
    }
    __builtin_amdgcn_s_setprio(0);

    const bool tail = kv0 >= q0;
    // per-group softmax + P write
#pragma unroll
    for (int g = 0; g < 2; ++g) {
      if (tail) {
#pragma unroll
        for (int cf = 0; cf < 4; ++cf) {
          const int kpos = kv0 + cf * 16 + lr;
#pragma unroll
          for (int r = 0; r < 4; ++r)
            sc[g][cf][r] = (kpos <= qb[g] + r) ? sc[g][cf][r] : -3e38f;
        }
      }
      float lmax[4];
#pragma unroll
      for (int r = 0; r < 4; ++r)
        lmax[r] = fmaxf(fmaxf(sc[g][0][r], sc[g][1][r]), fmaxf(sc[g][2][r], sc[g][3][r]));
      bool need = (lmax[0] > mrow[g][0] + 11.5416f) | (lmax[1] > mrow[g][1] + 11.5416f) |
                  (lmax[2] > mrow[g][2] + 11.5416f) | (lmax[3] > mrow[g][3] + 11.5416f);
      if (__any(need)) {
        float tm[4] = {lmax[0], lmax[1], lmax[2], lmax[3]};
#pragma unroll
        for (int off = 8; off; off >>= 1)
#pragma unroll
          for (int r = 0; r < 4; ++r) tm[r] = fmaxf(tm[r], __shfl_xor(tm[r], off));
#pragma unroll
        for (int r = 0; r < 4; ++r) {
          const float mn = fmaxf(mrow[g][r], tm[r]);
          const float alpha = __builtin_amdgcn_exp2f(mrow[g][r] - mn);
          mrow[g][r] = mn;
#pragma unroll
          for (int j = 0; j < 8; ++j) acc[g][j][r] *= alpha;
          acc_s[g][r] *= alpha;
        }
      }
#pragma unroll
      for (int r = 0; r < 4; ++r) {
        float p0 = __builtin_amdgcn_exp2f(sc[g][0][r] - mrow[g][r]) * g4[0];
        float p1 = __builtin_amdgcn_exp2f(sc[g][1][r] - mrow[g][r]) * g4[1];
        float p2 = __builtin_amdgcn_exp2f(sc[g][2][r] - mrow[g][r]) * g4[2];
        float p3 = __builtin_amdgcn_exp2f(sc[g][3][r] - mrow[g][r]) * g4[3];
        uint2 pk = { cvt_pk_bf16(p0, p1), cvt_pk_bf16(p2, p3) };
        *(uint2*)(&Ps[wave][g][lg * 4 + r][lr * 4]) = pk;
      }
    }
    // shared PV: each vb read feeds both row-groups
    __builtin_amdgcn_s_setprio(1);
#pragma unroll
    for (int ks = 0; ks < 2; ++ks) {
      bf16x8 pa0 = *(const bf16x8*)(&Ps[wave][0][lr][ks * 32 + lg * 8]);
      bf16x8 pa1 = *(const bf16x8*)(&Ps[wave][1][lr][ks * 32 + lg * 8]);
#pragma unroll
      for (int j = 0; j < 8; ++j) {
        const int d = j * 16 + lr;
        bf16x8 vb = *(const bf16x8*)(Vb + d * 64 + (((ks * 4 + lg) ^ (lr & 7)) * 8));
        acc[0][j] = __builtin_amdgcn_mfma_f32_16x16x32_bf16(pa0, vb, acc[0][j], 0, 0, 0);
        acc[1][j] = __builtin_amdgcn_mfma_f32_16x16x32_bf16(pa1, vb, acc[1][j], 0, 0, 0);
      }
      acc_s[0] = __builtin_amdgcn_mfma_f32_16x16x32_bf16(pa0, vb_ones, acc_s[0], 0, 0, 0);
      acc_s[1] = __builtin_amdgcn_mfma_f32_16x16x32_bf16(pa1, vb_ones, acc_s[1], 0, 0, 0);
    }
    __builtin_amdgcn_s_setprio(0);
    __builtin_amdgcn_s_barrier();
  }

  // partial epilogue: unnormalized numerator + (m, s) per row
  unsigned short* Nd = chunk ? N2 : N1;
#pragma unroll
  for (int g = 0; g < 2; ++g) {
#pragma unroll
    for (int j = 0; j < 8; ++j)
#pragma unroll
      for (int r = 0; r < 4; ++r)
        Nd[(size_t)(qb[g] + r) * DMODEL + h * HD + j * 16 + lr] = f2bf(acc[g][j][r]);
  }
  if (lr == 0) {
#pragma unroll
    for (int g = 0; g < 2; ++g)
#pragma unroll
      for (int r = 0; r < 4; ++r)
        Ms[(size_t)(chunk * 16 + h) * S_LEN + qb[g] + r] =
            make_float2(mrow[g][r], acc_s[g][r]);
  }
}

// ---------------- combine: O = (w1 N1 + w2 N2) / (w1 s1 + w2 s2) ----------------

__global__ __launch_bounds__(256) void k_comb(
    unsigned short* __restrict__ N1, const unsigned short* __restrict__ N2,
    const float2* __restrict__ Ms) {
  const int gid = blockIdx.x * 256 + threadIdx.x;
  const size_t e = (size_t)gid * 8;
  const int row = (int)(e >> 11);
  const int col = (int)(e & 2047);
  const int h = col >> 7;
  const float2 a = Ms[(size_t)h * S_LEN + row];
  const float2 b = Ms[(size_t)(16 + h) * S_LEN + row];
  const float m = fmaxf(a.x, b.x);
  const float w1 = __builtin_amdgcn_exp2f(a.x - m);
  const float w2 = __builtin_amdgcn_exp2f(b.x - m);
  const float inv = 1.0f / (w1 * a.y + w2 * b.y);
  us8 n1 = *(const us8*)(N1 + e);
  us8 n2 = *(const us8*)(N2 + e);
  us8 o;
#pragma unroll
  for (int k = 0; k < 8; ++k)
    o[k] = f2bf((w1 * bf2f(n1[k]) + w2 * bf2f(n2[k])) * inv);
  *(us8*)(N1 + e) = o;
}

// ---------------- launch ----------------

extern "C" void kernel_launch(void* const* d_in, const int* in_sizes, int n_in,
                              void* d_out, int out_size, void* d_ws, size_t ws_size,
                              hipStream_t stream) {
  (void)in_sizes; (void)n_in; (void)out_size; (void)ws_size;
  const float* hid  = (const float*)d_in[0];
  // d_in[1] = attention_mask (pure causal; recomputed inline, never read)
  const float* cosp = (const float*)d_in[2];
  const float* sinp = (const float*)d_in[3];
  const float* gate = (const float*)d_in[4];
  const float* Wq   = (const float*)d_in[5];
  const float* Wk   = (const float*)d_in[6];
  const float* Wv   = (const float*)d_in[7];
  const float* Wo   = (const float*)d_in[8];
  float* out = (float*)d_out;
  char* ws = (char*)d_ws;
  unsigned short* Xb   = (unsigned short*)(ws);                       // 16 MB  (dead after GEMM1)
  unsigned short* Wt   = (unsigned short*)(ws + (size_t)16777216);    // 12 MB  (dead after GEMM1)
  unsigned short* Wot  = (unsigned short*)(ws + (size_t)29360128);    //  8 MB  Wo^T
  unsigned short* QKV  = (unsigned short*)(ws + (size_t)37748736);    // 24 MB  [4096][3072] bf16 (roped)
  unsigned short* Oatt = (unsigned short*)(ws + (size_t)62914560);    // 16 MB  (N1 -> O in-place)
  unsigned short* Vt   = (unsigned short*)(ws + (size_t)79691776);    //  4 MB  [4][128][4096] bf16
  unsigned short* Np   = Xb;                                          // 16 MB  chunk-1 numerator
  float2* Ms           = (float2*)Wt;                                 //  1 MB  [2][16][4096] (m,s)

  k_prep<<<10752, 256, 0, stream>>>(hid, Xb, Wq, Wk, Wv, Wo, Wt, Wot);
  k_gemm_bt<1><<<dim3(32, 24), 256, 0, stream>>>(Xb, Wt, QKV, 4096, 3072, 2048, cosp, sinp);
  k_vt<<<512, 256, 0, stream>>>(QKV, Vt);
  k_attn<<<512, 512, 0, stream>>>(QKV, Vt, gate, Oatt, Np, Ms);
  k_comb<<<4096, 256, 0, stream>>>(Oatt, Np, Ms);
  k_gemm_bt<2><<<dim3(32, 16), 256, 0, stream>>>(Oatt, Wot, out, 4096, 2048, 2048, nullptr, nullptr);
}

// Round 17
// 243.530 us; speedup vs baseline: 1.0562x; 1.0145x over previous
//
#include <hip/hip_runtime.h>
#include <math.h>

#define S_LEN 4096
#define DMODEL 2048
#define NH 16
#define NKVH 4
#define HD 128
#define LDQKV 3072   // NH*HD + 2*NKVH*HD

typedef __attribute__((ext_vector_type(4))) float f32x4;
typedef __attribute__((ext_vector_type(8))) short bf16x8;
typedef __attribute__((ext_vector_type(8))) unsigned short us8;
typedef __attribute__((ext_vector_type(4))) unsigned short us4;

static __device__ __forceinline__ unsigned short f2bf(float f) {
  unsigned int u = __builtin_bit_cast(unsigned int, f);
  u += 0x7fffu + ((u >> 16) & 1u);
  return (unsigned short)(u >> 16);
}
static __device__ __forceinline__ float bf2f(unsigned short h) {
  unsigned int u = ((unsigned int)h) << 16;
  return __builtin_bit_cast(float, u);
}
static __device__ __forceinline__ unsigned int cvt_pk_bf16(float lo, float hi) {
  unsigned int r;
  asm("v_cvt_pk_bf16_f32 %0, %1, %2" : "=v"(r) : "v"(lo), "v"(hi));
  return r;
}

#define GLDS16(g, l) __builtin_amdgcn_global_load_lds( \
    (__attribute__((address_space(1))) void*)(g), \
    (__attribute__((address_space(3))) void*)(l), 16, 0, 0)

// ---------------- prep: cast hidden to bf16 + transpose all weights ----------------

__global__ __launch_bounds__(256) void k_prep(
    const float* __restrict__ hid, unsigned short* __restrict__ Xb,
    const float* __restrict__ Wq, const float* __restrict__ Wk,
    const float* __restrict__ Wv, const float* __restrict__ Wo,
    unsigned short* __restrict__ Wt, unsigned short* __restrict__ Wot) {
  __shared__ float tile[64][65];
  const int b = blockIdx.x, t = threadIdx.x;
  if (b < 8192) {
    int i = b * 256 + t;
    const float4* s = (const float4*)hid;
    float4 v = s[i];
    us4 o = { f2bf(v.x), f2bf(v.y), f2bf(v.z), f2bf(v.w) };
    *(us4*)(Xb + (size_t)i * 4) = o;
    return;
  }
  const int bb = b - 8192;
  const float* src;
  unsigned short* dst;
  int N, c;
  if (bb < 1024)      { src = Wq; dst = Wt;                       N = 2048; c = bb; }
  else if (bb < 1280) { src = Wk; dst = Wt + (size_t)2048 * 2048; N = 512;  c = bb - 1024; }
  else if (bb < 1536) { src = Wv; dst = Wt + (size_t)2560 * 2048; N = 512;  c = bb - 1280; }
  else                { src = Wo; dst = Wot;                      N = 2048; c = bb - 1536; }
  const int k0 = (c & 31) * 64, n0 = (c >> 5) * 64;
#pragma unroll
  for (int i = 0; i < 16; ++i) {
    int idx = t + i * 256;
    int r = idx >> 6, cc = idx & 63;
    tile[r][cc] = src[(size_t)(k0 + r) * N + n0 + cc];
  }
  __syncthreads();
#pragma unroll
  for (int i = 0; i < 16; ++i) {
    int idx = t + i * 256;
    int r = idx >> 6, cc = idx & 63;
    dst[(size_t)(n0 + r) * 2048 + k0 + cc] = f2bf(tile[cc][r]);
  }
}

// ---------------- V-transpose (permuted, gate-folded) + permuted gate array ----------------
// blocks [0,512): Vt[(c0+r)*S + s0+cc] = bf16( g[s0+pi(cc)] * V[s0+pi(cc)][c0+r] )
// blocks [512,528): garr[blk*64+c] = bf16(g[blk*64 + pi(c)]),  pi(c)=(c&3)*16+(c>>2)

__global__ __launch_bounds__(256) void k_vt(
    const unsigned short* __restrict__ QKV, const float* __restrict__ gate,
    unsigned short* __restrict__ Vt, unsigned short* __restrict__ garr) {
  __shared__ unsigned short tile[64][72];
  const int b = blockIdx.x, t = threadIdx.x;
  if (b < 512) {
    const int s0 = (b & 63) * 64, c0 = (b >> 6) * 64;
#pragma unroll
    for (int i = 0; i < 16; ++i) {
      int idx = t + i * 256;
      int r = idx >> 6, cc = idx & 63;
      tile[r][cc] = QKV[(size_t)(s0 + r) * LDQKV + DMODEL + NKVH * HD + c0 + cc];
    }
    __syncthreads();
#pragma unroll
    for (int i = 0; i < 16; ++i) {
      int idx = t + i * 256;
      int r = idx >> 6, cc = idx & 63;
      int pc = (cc & 3) * 16 + (cc >> 2);
      float gv = bf2f(tile[pc][r]) * gate[s0 + pc];
      Vt[(size_t)(c0 + r) * S_LEN + s0 + cc] = f2bf(gv);
    }
  } else {
    int gid = (b - 512) * 256 + t;   // 0..4095
    int blk = gid >> 6, c = gid & 63;
    garr[gid] = f2bf(gate[blk * 64 + (c & 3) * 16 + (c >> 2)]);
  }
}

// ---------------- GEMM: C[M][N] = A[M][K] * Bt[N][K]^T ----------------
// 128x128 tile, BK=32, 4 waves M-split (32 rows x 128 cols each), 3 blocks/CU.
// Proven m97-class structure — confirmed as the practical ceiling for these shapes.
// MODE 1: QKV epilogue (RoPE on Q/K in f32, bf16 out); MODE 2: f32 out.

template<int MODE>
__global__ __launch_bounds__(256) void k_gemm_bt(
    const unsigned short* __restrict__ A, const unsigned short* __restrict__ Bt,
    void* __restrict__ Cp, int M, int N, int K,
    const float* __restrict__ cp, const float* __restrict__ sp) {
  __shared__ __attribute__((aligned(16))) unsigned short As[128 * 32];
  __shared__ __attribute__((aligned(16))) unsigned short Bs[128 * 32];
  const int t = threadIdx.x;
  const int wave = t >> 6, lane = t & 63;
  const int lr = lane & 15, lg = lane >> 4;
  const int bm = blockIdx.x * 128, bn = blockIdx.y * 128;
  const int wr = wave * 32;
  f32x4 acc[2][8];
#pragma unroll
  for (int i = 0; i < 2; ++i)
#pragma unroll
    for (int j = 0; j < 8; ++j) acc[i][j] = (f32x4){0.f, 0.f, 0.f, 0.f};

  for (int k0 = 0; k0 < K; k0 += 32) {
    __syncthreads();
#pragma unroll
    for (int i = 0; i < 2; ++i) {
      const int cb = (wave * 2 + i) * 64;
      const int c = cb + lane;
      const int row = c >> 2, kc = c & 3;
      const int ksw = (kc ^ (row & 3)) * 8;
      GLDS16(A + (size_t)(bm + row) * K + k0 + ksw, (char*)As + cb * 16);
      GLDS16(Bt + (size_t)(bn + row) * K + k0 + ksw, (char*)Bs + cb * 16);
    }
    asm volatile("s_waitcnt vmcnt(0)" ::: "memory");
    __syncthreads();
    bf16x8 af[2], bfr[8];
#pragma unroll
    for (int mi = 0; mi < 2; ++mi) {
      const int row = wr + mi * 16 + lr;
      af[mi] = *(const bf16x8*)(As + row * 32 + ((lg ^ (lr & 3)) * 8));
    }
#pragma unroll
    for (int ni = 0; ni < 8; ++ni) {
      const int row = ni * 16 + lr;
      bfr[ni] = *(const bf16x8*)(Bs + row * 32 + ((lg ^ (lr & 3)) * 8));
    }
#pragma unroll
    for (int mi = 0; mi < 2; ++mi)
#pragma unroll
      for (int ni = 0; ni < 8; ++ni)
        acc[mi][ni] = __builtin_amdgcn_mfma_f32_16x16x32_bf16(af[mi], bfr[ni], acc[mi][ni], 0, 0, 0);
  }

  if (MODE == 1 && bn < NKVH * HD + DMODEL) {
    const float qs = bn < DMODEL ? 0.12751589341664477f : 1.0f;  // log2e/sqrt(128) on Q
    unsigned short* o = (unsigned short*)Cp;
#pragma unroll
    for (int mi = 0; mi < 2; ++mi)
#pragma unroll
      for (int r = 0; r < 4; ++r) {
        const int m = bm + wr + mi * 16 + lg * 4 + r;
#pragma unroll
        for (int ni = 0; ni < 4; ++ni) {
          const int d = ni * 16 + lr;
          const float c = cp[m * HD + d], s = sp[m * HD + d];
          const float x1 = acc[mi][ni][r], x2 = acc[mi][ni + 4][r];
          o[(size_t)m * N + bn + d]      = f2bf((x1 * c - x2 * s) * qs);
          o[(size_t)m * N + bn + d + 64] = f2bf((x2 * c + x1 * s) * qs);
        }
      }
    return;
  }
#pragma unroll
  for (int mi = 0; mi < 2; ++mi)
#pragma unroll
    for (int ni = 0; ni < 8; ++ni)
#pragma unroll
      for (int r = 0; r < 4; ++r) {
        const int m = bm + wr + mi * 16 + lg * 4 + r;
        const int n = bn + ni * 16 + lr;
        if (MODE == 2) ((float*)Cp)[(size_t)m * N + n] = acc[mi][ni][r];
        else ((unsigned short*)Cp)[(size_t)m * N + n] = f2bf(acc[mi][ni][r]);
      }
}

// ---------------- fused causal gated attention (v13: kv-split, gate folded into V') ----------------
// 512 blocks, heavy-first: bx -> st = 15-(bx>>5), h = (bx&31)>>1, chunk = bx&1.
// P = exp2(s-m) (no gate); V' = g*V; denominator via g-column MFMA from the
// LDS-resident permuted-gate array (8KB, staged once per block).
// Writes UNNORMALIZED partial numerator (bf16) + per-row (m, s) f32; k_comb merges.

#define STAGE_KV(kt_, buf_) do { \
  const int kv0_ = (kt_) * 64; \
  _Pragma("unroll") \
  for (int i_ = 0; i_ < 2; ++i_) { \
    const int cb_ = (wave * 2 + i_) * 64; \
    const int c_ = cb_ + lane; \
    { const int row_ = c_ >> 4, kc_ = c_ & 15; \
      GLDS16(Kp + (size_t)(kv0_ + row_) * LDQKV + ((kc_ ^ (row_ & 7)) * 8), \
             (char*)Ks[buf_] + cb_ * 16); } \
    { const int d_ = c_ >> 3, kc_ = c_ & 7; \
      GLDS16(Vp + (size_t)d_ * S_LEN + kv0_ + ((kc_ ^ (d_ & 7)) * 8), \
             (char*)Vs[buf_] + cb_ * 16); } \
  } \
} while (0)

__global__ __launch_bounds__(512) void k_attn(
    const unsigned short* __restrict__ QKV, const unsigned short* __restrict__ Vt,
    const unsigned short* __restrict__ garr, unsigned short* __restrict__ N1,
    unsigned short* __restrict__ N2, float2* __restrict__ Ms) {
  __shared__ __attribute__((aligned(16))) unsigned short Ks[2][64 * 128];
  __shared__ __attribute__((aligned(16))) unsigned short Vs[2][128 * 64];
  __shared__ __attribute__((aligned(16))) unsigned short Ps[8][2][16][72];
  __shared__ __attribute__((aligned(16))) unsigned short Lg[4096];
  const int bx = blockIdx.x;
  const int st = 15 - (bx >> 5);
  const int rem = bx & 31;
  const int h = rem >> 1, chunk = rem & 1;
  const int kvh = h >> 2;
  const int t = threadIdx.x, wave = t >> 6, lane = t & 63;
  const int lr = lane & 15, lg = lane >> 4;
  const unsigned short* Qp = QKV + h * HD;
  const unsigned short* Kp = QKV + DMODEL + kvh * HD;
  const unsigned short* Vp = Vt + (size_t)kvh * HD * S_LEN;

  // one-time: stage the 8KB permuted-gate array (1 load unit per wave;
  // drained by the first in-loop vmcnt+barrier before any PV uses it)
  GLDS16(garr + wave * 512 + lane * 8, (char*)Lg + wave * 1024);

  const int q0 = st * 256;
  const int half_nt = 2 * st + 2;
  const int kt_lo = chunk * half_nt, kt_hi = kt_lo + half_nt;
  const int qb[2] = { q0 + wave * 32 + lg * 4, q0 + wave * 32 + 16 + lg * 4 };

  bf16x8 qf[2][4];
#pragma unroll
  for (int g = 0; g < 2; ++g) {
    const size_t qoff = (size_t)(q0 + wave * 32 + g * 16 + lr) * LDQKV;
#pragma unroll
    for (int ks = 0; ks < 4; ++ks)
      qf[g][ks] = *(const bf16x8*)(Qp + qoff + ks * 32 + lg * 8);
  }
  f32x4 acc[2][8];
#pragma unroll
  for (int g = 0; g < 2; ++g)
#pragma unroll
    for (int j = 0; j < 8; ++j) acc[g][j] = (f32x4){0.f, 0.f, 0.f, 0.f};
  f32x4 acc_s[2] = { (f32x4){0.f, 0.f, 0.f, 0.f}, (f32x4){0.f, 0.f, 0.f, 0.f} };
  float mrow[2][4] = { {-3e38f, -3e38f, -3e38f, -3e38f}, {-3e38f, -3e38f, -3e38f, -3e38f} };
  f32x4 sc[2][4];

  STAGE_KV(kt_lo, kt_lo & 1);

  for (int kt = kt_lo; kt < kt_hi; ++kt) {
    const int kv0 = kt * 64;
    if (kt + 1 < kt_hi) {
      STAGE_KV(kt + 1, (kt + 1) & 1);
      asm volatile("s_waitcnt vmcnt(4)" ::: "memory");
    } else {
      asm volatile("s_waitcnt vmcnt(0)" ::: "memory");
    }
    __builtin_amdgcn_s_barrier();
    const unsigned short* Kb = Ks[kt & 1];
    const unsigned short* Vb = Vs[kt & 1];

    // dual QK^T: each kb read feeds both row-groups
    __builtin_amdgcn_s_setprio(1);
#pragma unroll
    for (int cf = 0; cf < 4; ++cf) {
      sc[0][cf] = (f32x4){0.f, 0.f, 0.f, 0.f};
      sc[1][cf] = (f32x4){0.f, 0.f, 0.f, 0.f};
      const int row = cf * 16 + lr;
#pragma unroll
      for (int ks = 0; ks < 4; ++ks) {
        bf16x8 kb = *(const bf16x8*)(Kb + row * 128 + (((ks * 4 + lg) ^ (lr & 7)) * 8));
        sc[0][cf] = __builtin_amdgcn_mfma_f32_16x16x32_bf16(qf[0][ks], kb, sc[0][cf], 0, 0, 0);
        sc[1][cf] = __builtin_amdgcn_mfma_f32_16x16x32_bf16(qf[1][ks], kb, sc[1][cf], 0, 0, 0);
      }
    }
    __builtin_amdgcn_s_setprio(0);

    const bool tail = kv0 >= q0;
    // per-group softmax + P write (P stored WITHOUT gate; V carries it)
#pragma unroll
    for (int g = 0; g < 2; ++g) {
      if (tail) {
#pragma unroll
        for (int cf = 0; cf < 4; ++cf) {
          const int kpos = kv0 + cf * 16 + lr;
#pragma unroll
          for (int r = 0; r < 4; ++r)
            sc[g][cf][r] = (kpos <= qb[g] + r) ? sc[g][cf][r] : -3e38f;
        }
      }
      float lmax[4];
#pragma unroll
      for (int r = 0; r < 4; ++r)
        lmax[r] = fmaxf(fmaxf(sc[g][0][r], sc[g][1][r]), fmaxf(sc[g][2][r], sc[g][3][r]));
      bool need = (lmax[0] > mrow[g][0] + 11.5416f) | (lmax[1] > mrow[g][1] + 11.5416f) |
                  (lmax[2] > mrow[g][2] + 11.5416f) | (lmax[3] > mrow[g][3] + 11.5416f);
      if (__any(need)) {
        float tm[4] = {lmax[0], lmax[1], lmax[2], lmax[3]};
#pragma unroll
        for (int off = 8; off; off >>= 1)
#pragma unroll
          for (int r = 0; r < 4; ++r) tm[r] = fmaxf(tm[r], __shfl_xor(tm[r], off));
#pragma unroll
        for (int r = 0; r < 4; ++r) {
          const float mn = fmaxf(mrow[g][r], tm[r]);
          const float alpha = __builtin_amdgcn_exp2f(mrow[g][r] - mn);
          mrow[g][r] = mn;
#pragma unroll
          for (int j = 0; j < 8; ++j) acc[g][j][r] *= alpha;
          acc_s[g][r] *= alpha;
        }
      }
#pragma unroll
      for (int r = 0; r < 4; ++r) {
        float p0 = __builtin_amdgcn_exp2f(sc[g][0][r] - mrow[g][r]);
        float p1 = __builtin_amdgcn_exp2f(sc[g][1][r] - mrow[g][r]);
        float p2 = __builtin_amdgcn_exp2f(sc[g][2][r] - mrow[g][r]);
        float p3 = __builtin_amdgcn_exp2f(sc[g][3][r] - mrow[g][r]);
        uint2 pk = { cvt_pk_bf16(p0, p1), cvt_pk_bf16(p2, p3) };
        *(uint2*)(&Ps[wave][g][lg * 4 + r][lr * 4]) = pk;
      }
    }
    // shared PV: each vb read feeds both row-groups; g-column MFMA = denominator
    __builtin_amdgcn_s_setprio(1);
#pragma unroll
    for (int ks = 0; ks < 2; ++ks) {
      bf16x8 pa0 = *(const bf16x8*)(&Ps[wave][0][lr][ks * 32 + lg * 8]);
      bf16x8 pa1 = *(const bf16x8*)(&Ps[wave][1][lr][ks * 32 + lg * 8]);
      bf16x8 gfrag = (bf16x8){0, 0, 0, 0, 0, 0, 0, 0};
      if (lr == 0) gfrag = *(const bf16x8*)(Lg + kv0 + ks * 32 + lg * 8);
#pragma unroll
      for (int j = 0; j < 8; ++j) {
        const int d = j * 16 + lr;
        bf16x8 vb = *(const bf16x8*)(Vb + d * 64 + (((ks * 4 + lg) ^ (lr & 7)) * 8));
        acc[0][j] = __builtin_amdgcn_mfma_f32_16x16x32_bf16(pa0, vb, acc[0][j], 0, 0, 0);
        acc[1][j] = __builtin_amdgcn_mfma_f32_16x16x32_bf16(pa1, vb, acc[1][j], 0, 0, 0);
      }
      acc_s[0] = __builtin_amdgcn_mfma_f32_16x16x32_bf16(pa0, gfrag, acc_s[0], 0, 0, 0);
      acc_s[1] = __builtin_amdgcn_mfma_f32_16x16x32_bf16(pa1, gfrag, acc_s[1], 0, 0, 0);
    }
    __builtin_amdgcn_s_setprio(0);
    __builtin_amdgcn_s_barrier();
  }

  // partial epilogue: unnormalized numerator + (m, s) per row
  unsigned short* Nd = chunk ? N2 : N1;
#pragma unroll
  for (int g = 0; g < 2; ++g) {
#pragma unroll
    for (int j = 0; j < 8; ++j)
#pragma unroll
      for (int r = 0; r < 4; ++r)
        Nd[(size_t)(qb[g] + r) * DMODEL + h * HD + j * 16 + lr] = f2bf(acc[g][j][r]);
  }
  if (lr == 0) {
#pragma unroll
    for (int g = 0; g < 2; ++g)
#pragma unroll
      for (int r = 0; r < 4; ++r)
        Ms[(size_t)(chunk * 16 + h) * S_LEN + qb[g] + r] =
            make_float2(mrow[g][r], acc_s[g][r]);
  }
}

// ---------------- combine: O = (w1 N1 + w2 N2) / (w1 s1 + w2 s2) ----------------

__global__ __launch_bounds__(256) void k_comb(
    unsigned short* __restrict__ N1, const unsigned short* __restrict__ N2,
    const float2* __restrict__ Ms) {
  const int gid = blockIdx.x * 256 + threadIdx.x;
  const size_t e = (size_t)gid * 8;
  const int row = (int)(e >> 11);
  const int col = (int)(e & 2047);
  const int h = col >> 7;
  const float2 a = Ms[(size_t)h * S_LEN + row];
  const float2 b = Ms[(size_t)(16 + h) * S_LEN + row];
  const float m = fmaxf(a.x, b.x);
  const float w1 = __builtin_amdgcn_exp2f(a.x - m);
  const float w2 = __builtin_amdgcn_exp2f(b.x - m);
  const float inv = 1.0f / (w1 * a.y + w2 * b.y);
  us8 n1 = *(const us8*)(N1 + e);
  us8 n2 = *(const us8*)(N2 + e);
  us8 o;
#pragma unroll
  for (int k = 0; k < 8; ++k)
    o[k] = f2bf((w1 * bf2f(n1[k]) + w2 * bf2f(n2[k])) * inv);
  *(us8*)(N1 + e) = o;
}

// ---------------- launch ----------------

extern "C" void kernel_launch(void* const* d_in, const int* in_sizes, int n_in,
                              void* d_out, int out_size, void* d_ws, size_t ws_size,
                              hipStream_t stream) {
  (void)in_sizes; (void)n_in; (void)out_size; (void)ws_size;
  const float* hid  = (const float*)d_in[0];
  // d_in[1] = attention_mask (pure causal; recomputed inline, never read)
  const float* cosp = (const float*)d_in[2];
  const float* sinp = (const float*)d_in[3];
  const float* gate = (const float*)d_in[4];
  const float* Wq   = (const float*)d_in[5];
  const float* Wk   = (const float*)d_in[6];
  const float* Wv   = (const float*)d_in[7];
  const float* Wo   = (const float*)d_in[8];
  float* out = (float*)d_out;
  char* ws = (char*)d_ws;
  unsigned short* Xb   = (unsigned short*)(ws);                       // 16 MB  (dead after GEMM1)
  unsigned short* Wt   = (unsigned short*)(ws + (size_t)16777216);    // 12 MB  (dead after GEMM1)
  unsigned short* Wot  = (unsigned short*)(ws + (size_t)29360128);    //  8 MB  Wo^T
  unsigned short* QKV  = (unsigned short*)(ws + (size_t)37748736);    // 24 MB  [4096][3072] bf16 (roped)
  unsigned short* Oatt = (unsigned short*)(ws + (size_t)62914560);    // 16 MB  (N1 -> O in-place)
  unsigned short* Vt   = (unsigned short*)(ws + (size_t)79691776);    //  4 MB  [4][128][4096] bf16 (g-folded)
  unsigned short* Np   = Xb;                                          // 16 MB  chunk-1 numerator
  float2* Ms           = (float2*)Wt;                                 //  1 MB  [2][16][4096] (m,s)
  unsigned short* garr = (unsigned short*)(ws + (size_t)18874368);    //  8 KB  permuted gate (dead Wt region, safely inside footprint)

  k_prep<<<10752, 256, 0, stream>>>(hid, Xb, Wq, Wk, Wv, Wo, Wt, Wot);
  k_gemm_bt<1><<<dim3(32, 24), 256, 0, stream>>>(Xb, Wt, QKV, 4096, 3072, 2048, cosp, sinp);
  k_vt<<<528, 256, 0, stream>>>(QKV, gate, Vt, garr);
  k_attn<<<512, 512, 0, stream>>>(QKV, Vt, garr, Oatt, Np, Ms);
  k_comb<<<4096, 256, 0, stream>>>(Oatt, Np, Ms);
  k_gemm_bt<2><<<dim3(32, 16), 256, 0, stream>>>(Oatt, Wot, out, 4096, 2048, 2048, nullptr, nullptr);
}